// Round 1
// baseline (553.508 us; speedup 1.0000x reference)
//
#include <hip/hip_runtime.h>
#include <hip/hip_bf16.h>

// ReadUnit: B=512, D=512, N=196
// Algebra: rai[b,n] = sum_d p[b,d]*kbp[b,d,n] + q[b,d]*kb[b,d,n]  (+ const_b, dropped: softmax-invariant)
//   where p = (ms@Wmem^T + bmem) * v[:, :D],  q = v[:, D:],  v = (ctrl*Wattn) @ Wcat
// out[b,d] = sum_n softmax(rai)[n] * kb[b,d,n]
// Single pass over kb/kbp (411 MB total) via chunked flash-style softmax (no rescale needed,
// rai is O(8) so exp() can't overflow fp32).

constexpr int D = 512;
constexpr int N = 196;

// ---------------- Phase A: two small fp32 GEMMs into workspace ----------------
// blocks 0..63   : mem[b,d] = sum_k ms[b,k]*Wmem[d,k] + bmem[d]      (512x512)
// blocks 64..191 : v[b,e]   = sum_k ctrl[b,k]*Wattn[k]*Wcat[k,e]     (512x1024)
__global__ __launch_bounds__(256) void phase_a(
    const float* __restrict__ ms, const float* __restrict__ ctrl,
    const float* __restrict__ Wmem, const float* __restrict__ bmem,
    const float* __restrict__ Wcat, const float* __restrict__ Wattn,
    float* __restrict__ mem_ws, float* __restrict__ v_ws)
{
    constexpr int PAD = 68;               // 68*4=272 B row stride: 16B-aligned, conflict-free
    __shared__ float As[16 * PAD];
    __shared__ float Bs[16 * PAD];

    const int bid = blockIdx.x;
    const int t   = threadIdx.x;
    const int tx  = t & 15, ty = t >> 4;

    const bool g1 = (bid < 64);
    int tile_m, tile_n;
    if (g1) { tile_m = (bid >> 3) * 64; tile_n = (bid & 7) * 64; }
    else    { int bb = bid - 64; tile_m = (bb >> 4) * 64; tile_n = (bb & 15) * 64; }

    float acc[4][4] = {};

    for (int k0 = 0; k0 < 512; k0 += 16) {
        // ---- stage A tile: As[k][m] = A[tile_m+m][k0+k]
        {
            const int k = t & 15;
            const int mbase = t >> 4;
#pragma unroll
            for (int r = 0; r < 4; r++) {
                const int m = mbase + 16 * r;
                const int row = tile_m + m;
                float a;
                if (g1) a = ms[row * 512 + k0 + k];
                else    a = ctrl[row * 512 + k0 + k] * Wattn[k0 + k];
                As[k * PAD + m] = a;
            }
        }
        // ---- stage B tile: Bs[k][n]
        if (g1) {
            const int k = t & 15;
            const int nbase = t >> 4;
#pragma unroll
            for (int r = 0; r < 4; r++) {
                const int n = nbase + 16 * r;
                Bs[k * PAD + n] = Wmem[(tile_n + n) * 512 + k0 + k];  // transposed
            }
        } else {
            const int n = t & 63;
            const int kbase = t >> 6;
#pragma unroll
            for (int r = 0; r < 4; r++) {
                const int k = kbase + 4 * r;
                Bs[k * PAD + n] = Wcat[(k0 + k) * 1024 + tile_n + n];
            }
        }
        __syncthreads();
#pragma unroll
        for (int k = 0; k < 16; k++) {
            const float4 av = *reinterpret_cast<const float4*>(&As[k * PAD + ty * 4]);
            const float4 bv = *reinterpret_cast<const float4*>(&Bs[k * PAD + tx * 4]);
            const float a[4] = {av.x, av.y, av.z, av.w};
            const float bb[4] = {bv.x, bv.y, bv.z, bv.w};
#pragma unroll
            for (int i = 0; i < 4; i++)
#pragma unroll
                for (int j = 0; j < 4; j++)
                    acc[i][j] += a[i] * bb[j];
        }
        __syncthreads();
    }

    if (g1) {
#pragma unroll
        for (int i = 0; i < 4; i++) {
            const int row = tile_m + ty * 4 + i;
#pragma unroll
            for (int j = 0; j < 4; j++) {
                const int col = tile_n + tx * 4 + j;
                mem_ws[row * 512 + col] = acc[i][j] + bmem[col];
            }
        }
    } else {
#pragma unroll
        for (int i = 0; i < 4; i++) {
            const int row = tile_m + ty * 4 + i;
#pragma unroll
            for (int j = 0; j < 4; j++) {
                const int col = tile_n + tx * 4 + j;
                v_ws[row * 1024 + col] = acc[i][j];
            }
        }
    }
}

// ---------------- Phase B: fused streaming softmax-read, single pass over kb/kbp ----------------
// One block per batch b. Chunks of C=14 n-columns staged in LDS (196 = 14*14, exact).
__global__ __launch_bounds__(256, 2) void phase_b(
    const float* __restrict__ kb,    // [B, D, N]
    const float* __restrict__ kbp,   // [B, D, N]
    const float* __restrict__ mem_ws,// [B, D]
    const float* __restrict__ v_ws,  // [B, 2D]
    float* __restrict__ out)         // [B, D]
{
    constexpr int C = 14;
    constexpr int P = 516;           // LDS row stride (floats): (4n+d)%32 pattern, <=2-way conflicts
    __shared__ float kbs[C * P];     // [n][d] kb chunk
    __shared__ float kps[C * P];     // [n][d] kb_proj chunk
    __shared__ float rai_s[C];

    const int b    = blockIdx.x;
    const int t    = threadIdx.x;
    const int lane = t & 63;
    const int wave = t >> 6;

    const float* kb_b  = kb  + (size_t)b * D * N;
    const float* kbp_b = kbp + (size_t)b * D * N;

    // preload p[d], q[d] for this lane's d-slice (d = lane + 64k)
    float p_r[8], q_r[8];
#pragma unroll
    for (int k = 0; k < 8; k++) {
        const int d = lane + 64 * k;
        const float m  = mem_ws[b * D + d];
        const float v1 = v_ws[b * 2 * D + d];
        p_r[k] = m * v1;
        q_r[k] = v_ws[b * 2 * D + D + d];
    }

    float acc0 = 0.f, acc1 = 0.f, L = 0.f;

    for (int c = 0; c < 14; c++) {
        const int n0 = c * C;
        // ---- stage chunk: 512 x 14 elements per array, 28 per thread
#pragma unroll
        for (int i = 0; i < 28; i++) {
            const int idx = i * 256 + t;
            const int d = idx / 14;
            const int n = idx - d * 14;
            const size_t g = (size_t)d * N + n0 + n;
            kps[n * P + d] = kbp_b[g];
            kbs[n * P + d] = kb_b[g];
        }
        __syncthreads();

        // ---- (a) rai[n] for this chunk: wave w handles n = 4w..4w+3 (wave 3: 12,13)
#pragma unroll
        for (int j = 0; j < 4; j++) {
            const int n = wave * 4 + j;
            if (n < C) {
                float s = 0.f;
#pragma unroll
                for (int k = 0; k < 8; k++) {
                    const int d = lane + 64 * k;
                    s += p_r[k] * kps[n * P + d] + q_r[k] * kbs[n * P + d];
                }
#pragma unroll
                for (int m = 32; m; m >>= 1) s += __shfl_xor(s, m, 64);
                if (lane == 0) rai_s[n] = s;
            }
        }
        __syncthreads();

        // ---- (b) weights + accumulate (every thread owns d = t and d = t+256)
        float w[C];
        float wsum = 0.f;
#pragma unroll
        for (int n = 0; n < C; n++) { w[n] = __expf(rai_s[n]); wsum += w[n]; }
        L += wsum;
#pragma unroll
        for (int n = 0; n < C; n++) {
            acc0 += w[n] * kbs[n * P + t];
            acc1 += w[n] * kbs[n * P + t + 256];
        }
        __syncthreads();  // protect LDS before next stage
    }

    const float inv = 1.0f / L;
    out[b * D + t]       = acc0 * inv;
    out[b * D + t + 256] = acc1 * inv;
}

extern "C" void kernel_launch(void* const* d_in, const int* in_sizes, int n_in,
                              void* d_out, int out_size, void* d_ws, size_t ws_size,
                              hipStream_t stream) {
    const float* ms    = (const float*)d_in[0];  // memory_state [512,512]
    const float* kb    = (const float*)d_in[1];  // knowledge_base [512,512,196]
    const float* ctrl  = (const float*)d_in[2];  // ctrl_state [512,512]
    const float* kbp   = (const float*)d_in[3];  // kb_proj [512,512,196]
    const float* Wmem  = (const float*)d_in[4];  // [512,512]
    const float* bmem  = (const float*)d_in[5];  // [512]
    const float* Wcat  = (const float*)d_in[6];  // [512,1024]
    // d_in[7] = b_cat  : softmax-invariant, unused
    const float* Wattn = (const float*)d_in[8];  // [512]
    // d_in[9] = b_attn : softmax-invariant, unused

    float* mem_ws = (float*)d_ws;                // 512*512 floats
    float* v_ws   = mem_ws + 512 * 512;          // 512*1024 floats

    phase_a<<<192, 256, 0, stream>>>(ms, ctrl, Wmem, bmem, Wcat, Wattn, mem_ws, v_ws);
    phase_b<<<512, 256, 0, stream>>>(kb, kbp, mem_ws, v_ws, (float*)d_out);
}

// Round 2
// 545.747 us; speedup vs baseline: 1.0142x; 1.0142x over previous
//
#include <hip/hip_runtime.h>
#include <hip/hip_bf16.h>

// ReadUnit: B=512, D=512, N=196
// rai[b,n] = sum_d p[b,d]*kbp[b,d,n] + q[b,d]*kb[b,d,n]   (+const_b, softmax-invariant)
//   p = (ms@Wmem^T + bmem) * v[:, :D],  q = v[:, D:],  v = (ctrl*Wattn) @ Wcat
// out[b,d] = sum_n softmax(rai)[n] * kb[b,d,n]
//
// Two-pass: k_rai streams kb+kbp once (dense float4 rows, kbp nontemporal so L3
// keeps kb), k_out re-reads kb (reverse batch order to hit L3 tail). 196 = 49
// float4 exactly, rows 16B-aligned -> zero over-fetch.

constexpr int D = 512;
constexpr int N = 196;
constexpr int NF4 = 49;  // N/4

using f4 = __attribute__((ext_vector_type(4))) float;

// ---------------- Phase A: two small fp32 GEMMs into workspace ----------------
__global__ __launch_bounds__(256) void phase_a(
    const float* __restrict__ ms, const float* __restrict__ ctrl,
    const float* __restrict__ Wmem, const float* __restrict__ bmem,
    const float* __restrict__ Wcat, const float* __restrict__ Wattn,
    float* __restrict__ mem_ws, float* __restrict__ v_ws)
{
    constexpr int PAD = 68;
    __shared__ float As[16 * PAD];
    __shared__ float Bs[16 * PAD];

    const int bid = blockIdx.x;
    const int t   = threadIdx.x;
    const int tx  = t & 15, ty = t >> 4;

    const bool g1 = (bid < 64);
    int tile_m, tile_n;
    if (g1) { tile_m = (bid >> 3) * 64; tile_n = (bid & 7) * 64; }
    else    { int bb = bid - 64; tile_m = (bb >> 4) * 64; tile_n = (bb & 15) * 64; }

    float acc[4][4] = {};

    for (int k0 = 0; k0 < 512; k0 += 16) {
        {
            const int k = t & 15;
            const int mbase = t >> 4;
#pragma unroll
            for (int r = 0; r < 4; r++) {
                const int m = mbase + 16 * r;
                const int row = tile_m + m;
                float a;
                if (g1) a = ms[row * 512 + k0 + k];
                else    a = ctrl[row * 512 + k0 + k] * Wattn[k0 + k];
                As[k * PAD + m] = a;
            }
        }
        if (g1) {
            const int k = t & 15;
            const int nbase = t >> 4;
#pragma unroll
            for (int r = 0; r < 4; r++) {
                const int n = nbase + 16 * r;
                Bs[k * PAD + n] = Wmem[(tile_n + n) * 512 + k0 + k];
            }
        } else {
            const int n = t & 63;
            const int kbase = t >> 6;
#pragma unroll
            for (int r = 0; r < 4; r++) {
                const int k = kbase + 4 * r;
                Bs[k * PAD + n] = Wcat[(k0 + k) * 1024 + tile_n + n];
            }
        }
        __syncthreads();
#pragma unroll
        for (int k = 0; k < 16; k++) {
            const float4 av = *reinterpret_cast<const float4*>(&As[k * PAD + ty * 4]);
            const float4 bv = *reinterpret_cast<const float4*>(&Bs[k * PAD + tx * 4]);
            const float a[4] = {av.x, av.y, av.z, av.w};
            const float bb[4] = {bv.x, bv.y, bv.z, bv.w};
#pragma unroll
            for (int i = 0; i < 4; i++)
#pragma unroll
                for (int j = 0; j < 4; j++)
                    acc[i][j] += a[i] * bb[j];
        }
        __syncthreads();
    }

    if (g1) {
#pragma unroll
        for (int i = 0; i < 4; i++) {
            const int row = tile_m + ty * 4 + i;
#pragma unroll
            for (int j = 0; j < 4; j++) {
                const int col = tile_n + tx * 4 + j;
                mem_ws[row * 512 + col] = acc[i][j] + bmem[col];
            }
        }
    } else {
#pragma unroll
        for (int i = 0; i < 4; i++) {
            const int row = tile_m + ty * 4 + i;
#pragma unroll
            for (int j = 0; j < 4; j++) {
                const int col = tile_n + tx * 4 + j;
                v_ws[row * 1024 + col] = acc[i][j];
            }
        }
    }
}

// ---------------- K1: rai partials, one pass over kb+kbp, fully coalesced ----------------
// 1024 blocks: (b, d-half). Lane l<49 owns float4-column l; each wave-instr reads
// one contiguous 784B row. kbp is dead after this kernel -> nontemporal.
__global__ __launch_bounds__(256) void k_rai(
    const f4* __restrict__ kb, const f4* __restrict__ kbp,
    const float* __restrict__ mem_ws, const float* __restrict__ v_ws,
    float* __restrict__ rai_ws)
{
    __shared__ float p_s[256];
    __shared__ float q_s[256];
    __shared__ float part[4][200];

    const int bid = blockIdx.x;
    const int b   = bid >> 1;
    const int s   = bid & 1;
    const int d0  = s * 256;
    const int t    = threadIdx.x;
    const int lane = t & 63;
    const int w    = t >> 6;

    {
        const int d = d0 + t;
        p_s[t] = mem_ws[b * D + d] * v_ws[b * 2 * D + d];
        q_s[t] = v_ws[b * 2 * D + D + d];
    }
    __syncthreads();

    const int lc = (lane < NF4) ? lane : (NF4 - 1);  // lanes 49..63 duplicate col 48
    const f4* kb_b  = kb  + (size_t)b * (D * NF4);
    const f4* kbp_b = kbp + (size_t)b * (D * NF4);

    float a0 = 0.f, a1 = 0.f, a2 = 0.f, a3 = 0.f;
    const int dw = d0 + w * 64;  // each wave: 64 contiguous rows
#pragma unroll 4
    for (int r = 0; r < 64; r++) {
        const int d = dw + r;
        const f4 vp = __builtin_nontemporal_load(&kbp_b[(size_t)d * NF4 + lc]);
        const f4 vk = kb_b[(size_t)d * NF4 + lc];
        const float pd = p_s[d - d0];
        const float qd = q_s[d - d0];
        a0 += pd * vp.x + qd * vk.x;
        a1 += pd * vp.y + qd * vk.y;
        a2 += pd * vp.z + qd * vk.z;
        a3 += pd * vp.w + qd * vk.w;
    }

    if (lane < NF4) {
        part[w][4 * lane + 0] = a0;
        part[w][4 * lane + 1] = a1;
        part[w][4 * lane + 2] = a2;
        part[w][4 * lane + 3] = a3;
    }
    __syncthreads();

    if (t < N) {
        const float r = part[0][t] + part[1][t] + part[2][t] + part[3][t];
        rai_ws[(size_t)(b * 2 + s) * N + t] = r;
    }
}

// ---------------- K2: softmax + weighted sum, one pass over kb ----------------
// Reverse batch order: k_rai finished with high b -> those kb slabs are L3-hot.
__global__ __launch_bounds__(256) void k_out(
    const f4* __restrict__ kb, const float* __restrict__ rai_ws,
    float* __restrict__ out)
{
    __shared__ float w_s[N];
    __shared__ float red[4];
    __shared__ float out_s[D];

    const int b    = 511 - (int)blockIdx.x;
    const int t    = threadIdx.x;
    const int lane = t & 63;
    const int w    = t >> 6;

    float e = 0.f;
    if (t < N) {
        const float r = rai_ws[(size_t)(b * 2) * N + t]
                      + rai_ws[(size_t)(b * 2 + 1) * N + t];
        e = __expf(r);           // rai is O(+-10): no max-subtraction needed in fp32
        w_s[t] = e;
    }
    float ssum = e;
#pragma unroll
    for (int m = 32; m; m >>= 1) ssum += __shfl_xor(ssum, m, 64);
    if (lane == 0) red[w] = ssum;
    __syncthreads();

    const float inv = 1.0f / (red[0] + red[1] + red[2] + red[3]);

    f4 wv = {0.f, 0.f, 0.f, 0.f};
    if (lane < NF4) {            // lanes >=49: wv=0 -> contribute 0 to reduction
        wv.x = w_s[4 * lane + 0] * inv;
        wv.y = w_s[4 * lane + 1] * inv;
        wv.z = w_s[4 * lane + 2] * inv;
        wv.w = w_s[4 * lane + 3] * inv;
    }

    const int lc = (lane < NF4) ? lane : (NF4 - 1);
    const f4* kb_b = kb + (size_t)b * (D * NF4);
    const int dw = w * 128;      // each wave: 128 contiguous rows
#pragma unroll 4
    for (int r = 0; r < 128; r++) {
        const int d = dw + r;
        const f4 v = kb_b[(size_t)d * NF4 + lc];
        float sc = v.x * wv.x + v.y * wv.y + v.z * wv.z + v.w * wv.w;
#pragma unroll
        for (int m = 32; m; m >>= 1) sc += __shfl_xor(sc, m, 64);
        if (lane == 0) out_s[d] = sc;
    }
    __syncthreads();

    out[(size_t)b * D + t]       = out_s[t];
    out[(size_t)b * D + 256 + t] = out_s[256 + t];
}

extern "C" void kernel_launch(void* const* d_in, const int* in_sizes, int n_in,
                              void* d_out, int out_size, void* d_ws, size_t ws_size,
                              hipStream_t stream) {
    const float* ms    = (const float*)d_in[0];
    const float* kb    = (const float*)d_in[1];
    const float* ctrl  = (const float*)d_in[2];
    const float* kbp   = (const float*)d_in[3];
    const float* Wmem  = (const float*)d_in[4];
    const float* bmem  = (const float*)d_in[5];
    const float* Wcat  = (const float*)d_in[6];
    const float* Wattn = (const float*)d_in[8];

    float* mem_ws = (float*)d_ws;                 // 512*512
    float* v_ws   = mem_ws + 512 * 512;           // 512*1024
    float* rai_ws = v_ws + 512 * 1024;            // 512*2*196

    phase_a<<<192, 256, 0, stream>>>(ms, ctrl, Wmem, bmem, Wcat, Wattn, mem_ws, v_ws);
    k_rai<<<1024, 256, 0, stream>>>((const f4*)kb, (const f4*)kbp, mem_ws, v_ws, rai_ws);
    k_out<<<512, 256, 0, stream>>>((const f4*)kb, rai_ws, (float*)d_out);
}